// Round 3
// baseline (1997.858 us; speedup 1.0000x reference)
//
#include <hip/hip_runtime.h>
#include <math.h>

#define NN 50000
#define NE 1600000
#define NG 256
#define IND 128
#define HID 64
#define NREL 3
#define SLOPE 0.2f
#define XRS 192        // XR row stride (3 relations * 64)
#define NRS 832        // node_rep row stride = 13*64

__device__ __forceinline__ float wred_max(float v){
  #pragma unroll
  for (int o = 32; o; o >>= 1) v = fmaxf(v, __shfl_xor(v, o));
  return v;
}
__device__ __forceinline__ float wred_sum(float v){
  #pragma unroll
  for (int o = 32; o; o >>= 1) v += __shfl_xor(v, o);
  return v;
}

// ---- CSR build --------------------------------------------------------------

__global__ void hist_kernel(const int* __restrict__ dst, int* __restrict__ cnts){
  int e = blockIdx.x * blockDim.x + threadIdx.x;
  if (e < NE) atomicAdd(&cnts[dst[e]], 1);
}

// hierarchical exclusive scan of cnts[NN] -> rowp[NN+1]
__global__ void scan1_kernel(const int* __restrict__ cnts, int* __restrict__ rowp,
                             int* __restrict__ bsum){
  __shared__ int ws[16];
  int b = blockIdx.x, tid = threadIdx.x;
  int i = b * 1024 + tid;
  int lane = tid & 63, wid = tid >> 6;
  int v = (i < NN) ? cnts[i] : 0;
  int x = v;
  #pragma unroll
  for (int o = 1; o < 64; o <<= 1){ int t = __shfl_up(x, o); if (lane >= o) x += t; }
  if (lane == 63) ws[wid] = x;
  __syncthreads();
  if (tid < 16){
    int y = ws[tid];
    #pragma unroll
    for (int o = 1; o < 16; o <<= 1){ int t = __shfl_up(y, o); if (tid >= o) y += t; }
    ws[tid] = y;
  }
  __syncthreads();
  int off = (wid > 0) ? ws[wid - 1] : 0;
  x += off;                         // inclusive within block
  if (i < NN) rowp[i] = x - v;      // exclusive within block
  if (tid == 1023) bsum[b] = x;     // block total
}

__global__ void scan2_kernel(int* __restrict__ bsum, int* __restrict__ rowp, int nb){
  int tid = threadIdx.x;
  int v = (tid < nb) ? bsum[tid] : 0;
  int x = v;
  #pragma unroll
  for (int o = 1; o < 64; o <<= 1){ int t = __shfl_up(x, o); if (tid >= o) x += t; }
  if (tid < nb) bsum[tid] = x - v;  // exclusive block offsets
  if (tid == 63) rowp[NN] = x;      // grand total
}

__global__ void scan3_kernel(int* __restrict__ rowp, const int* __restrict__ bsum){
  int i = blockIdx.x * 1024 + threadIdx.x;
  if (i < NN) rowp[i] += bsum[blockIdx.x];
}

__global__ void scatter_kernel(const int* __restrict__ src, const int* __restrict__ dst,
                               const int* __restrict__ et, const int* __restrict__ rowp,
                               int* __restrict__ fill, int* __restrict__ csr){
  int e = blockIdx.x * blockDim.x + threadIdx.x;
  if (e >= NE) return;
  int d = dst[e];
  int pos = atomicAdd(&fill[d], 1);
  csr[rowp[d] + pos] = src[e] | (et[e] << 24);
}

// graph boundaries from sorted batch_index: gst[g] = first node with batch >= g
__global__ void gstart_kernel(const int* __restrict__ batch, int* __restrict__ gst){
  int n = blockIdx.x * blockDim.x + threadIdx.x;
  if (n > NN) return;
  int bc = (n < NN) ? batch[n] : NG;
  int bp = (n == 0) ? -1 : batch[n - 1];
  for (int g = bp + 1; g <= bc; ++g) gst[g] = n;
}

// ---- fp32 GEMM: XR[n][r*64+h] = sum_k x[n][k] * W[r][k][h] ------------------
// One block: 64 rows x 192 cols (all 3 relations share the A tile).
// Epilogue: QK[n][r] = xr_r[n].q ; QK[n][3+r] = xr_r[n].k  (shfl butterfly)
__global__ __launch_bounds__(256) void mm_kernel(
    const float* __restrict__ x, int ldx, int K,
    const float* __restrict__ W, const float* __restrict__ qv, const float* __restrict__ kv,
    float* __restrict__ XR, float* __restrict__ QK){
  __shared__ float As[16][68];   // [k][row]
  __shared__ float Bs[16][196];  // [k][col 0..191]
  int tid = threadIdx.x;
  int tx = tid & 15, ty = tid >> 4;
  int row0 = blockIdx.x * 64;
  float acc[4][12] = {};         // [row i][rel r*4 + j], col = r*64 + tx*4 + j
  int lr = tid >> 2, lc = (tid & 3) << 2;   // A: row lr, k-quad lc
  int br = tid >> 4, bc = (tid & 15) << 2;  // B: k br, col-quad bc (per relation)
  for (int k0 = 0; k0 < K; k0 += 16){
    float4 av = make_float4(0.f, 0.f, 0.f, 0.f);
    if (row0 + lr < NN) av = *(const float4*)(x + (size_t)(row0 + lr) * ldx + k0 + lc);
    As[lc + 0][lr] = av.x; As[lc + 1][lr] = av.y; As[lc + 2][lr] = av.z; As[lc + 3][lr] = av.w;
    #pragma unroll
    for (int r = 0; r < NREL; ++r)
      *(float4*)&Bs[br][r * 64 + bc] = *(const float4*)(W + ((size_t)r * K + k0 + br) * HID + bc);
    __syncthreads();
    #pragma unroll
    for (int kk = 0; kk < 16; ++kk){
      float4 a4 = *(float4*)&As[kk][ty << 2];
      float aa[4] = {a4.x, a4.y, a4.z, a4.w};
      #pragma unroll
      for (int r = 0; r < NREL; ++r){
        float4 b4 = *(float4*)&Bs[kk][r * 64 + (tx << 2)];
        float bb[4] = {b4.x, b4.y, b4.z, b4.w};
        #pragma unroll
        for (int i = 0; i < 4; ++i)
          #pragma unroll
          for (int j = 0; j < 4; ++j)
            acc[i][j + r * 4] = fmaf(aa[i], bb[j], acc[i][j + r * 4]);
      }
    }
    __syncthreads();
  }
  // store XR
  #pragma unroll
  for (int i = 0; i < 4; ++i){
    int row = row0 + (ty << 2) + i;
    if (row < NN){
      #pragma unroll
      for (int r = 0; r < NREL; ++r)
        *(float4*)(XR + (size_t)row * XRS + r * HID + (tx << 2)) =
            make_float4(acc[i][r * 4], acc[i][r * 4 + 1], acc[i][r * 4 + 2], acc[i][r * 4 + 3]);
    }
  }
  // epilogue: q/k dots, reduce over tx (16 consecutive lanes) via shfl butterfly
  float q4[4], k4[4];
  #pragma unroll
  for (int j = 0; j < 4; ++j){ q4[j] = qv[(tx << 2) + j]; k4[j] = kv[(tx << 2) + j]; }
  #pragma unroll
  for (int r = 0; r < NREL; ++r){
    float pq[4], pk[4];
    #pragma unroll
    for (int i = 0; i < 4; ++i){
      float sq = 0.f, sk = 0.f;
      #pragma unroll
      for (int j = 0; j < 4; ++j){
        sq = fmaf(acc[i][r * 4 + j], q4[j], sq);
        sk = fmaf(acc[i][r * 4 + j], k4[j], sk);
      }
      pq[i] = sq; pk[i] = sk;
    }
    #pragma unroll
    for (int o = 1; o < 16; o <<= 1){
      #pragma unroll
      for (int i = 0; i < 4; ++i){
        pq[i] += __shfl_xor(pq[i], o);
        pk[i] += __shfl_xor(pk[i], o);
      }
    }
    if (tx == 0){
      #pragma unroll
      for (int i = 0; i < 4; ++i){
        int row = row0 + (ty << 2) + i;
        if (row < NN){
          QK[row * 8 + r] = pq[i];
          QK[row * 8 + 3 + r] = pk[i];
        }
      }
    }
  }
}

// ---- edge softmax + aggregation: one wave per dst node ----------------------

__global__ __launch_bounds__(256) void edge_kernel(
    const float* __restrict__ XR, const float* __restrict__ QK,
    const int* __restrict__ csr, const int* __restrict__ rowp,
    const float* __restrict__ bias, float* __restrict__ out){
  int wid = blockIdx.x * 4 + (threadIdx.x >> 6);
  int lane = threadIdx.x & 63;
  if (wid >= NN) return;
  int beg = rowp[wid], end = rowp[wid + 1];
  float bv = bias[lane];
  float* op = out + (size_t)wid * NRS + lane;
  if (beg == end){ *op = bv; return; }
  float q0 = QK[wid * 8], q1 = QK[wid * 8 + 1], q2 = QK[wid * 8 + 2];
  // pass 1: online softmax stats (m, s) over incoming edges
  float m = -INFINITY, s = 0.f;
  for (int c = beg; c < end; c += 64){
    int idx = c + lane;
    float l = -INFINITY;
    if (idx < end){
      int pk = csr[idx];
      int sn = pk & 0xFFFFFF, et = pk >> 24;
      float lg = (et == 0 ? q0 : (et == 1 ? q1 : q2)) + QK[sn * 8 + 3 + et];
      l = lg >= 0.f ? lg : lg * SLOPE;
    }
    float mnew = fmaxf(m, wred_max(l));
    float ps = wred_sum((idx < end) ? __expf(l - mnew) : 0.f);
    s = s * __expf(m - mnew) + ps;
    m = mnew;
  }
  float inv = 1.f / (s + 1e-16f);
  // pass 2: weighted gather-accumulate, lane = feature
  float acc = 0.f;
  for (int c = beg; c < end; c += 64){
    int idx = c + lane;
    int off = 0; float wgt = 0.f;
    if (idx < end){
      int pk = csr[idx];
      int sn = pk & 0xFFFFFF, et = pk >> 24;
      float lg = (et == 0 ? q0 : (et == 1 ? q1 : q2)) + QK[sn * 8 + 3 + et];
      float l = lg >= 0.f ? lg : lg * SLOPE;
      wgt = __expf(l - m) * inv;
      off = sn * XRS + et * HID;
    }
    int cnt = min(64, end - c);
    #pragma unroll 4
    for (int j = 0; j < cnt; ++j){
      float wj = __uint_as_float(__builtin_amdgcn_readlane(__float_as_uint(wgt), j));
      int oj = __builtin_amdgcn_readlane(off, j);
      acc = fmaf(wj, XR[oj + lane], acc);
    }
  }
  *op = acc + bv;
}

// ---- graph-level softmax aggregation ---------------------------------------
// grid (NG, 13); block 256 = 4 node-parallel waves x 64 features

__global__ __launch_bounds__(256) void agg_kernel(
    const float* __restrict__ nr, const int* __restrict__ gst,
    const float* __restrict__ tp, float* __restrict__ out){
  __shared__ float red[4][64];
  __shared__ float red2[4][64];
  int g = blockIdx.x;
  int lane = threadIdx.x & 63;
  int w = threadIdx.x >> 6;
  int f = blockIdx.y * 64 + lane;
  int s = gst[g], e = gst[g + 1];
  float tval = tp[0];
  float m = -INFINITY;
  for (int n = s + w; n < e; n += 4)
    m = fmaxf(m, nr[(size_t)n * NRS + f] * tval);
  red[w][lane] = m;
  __syncthreads();
  m = fmaxf(fmaxf(red[0][lane], red[1][lane]), fmaxf(red[2][lane], red[3][lane]));
  float ss = 0.f, acc = 0.f;
  for (int n = s + w; n < e; n += 4){
    float v = nr[(size_t)n * NRS + f];
    float ee = __expf(v * tval - m);
    ss += ee; acc = fmaf(v, ee, acc);
  }
  __syncthreads();
  red[w][lane] = ss; red2[w][lane] = acc;
  __syncthreads();
  if (w == 0){
    ss = red[0][lane] + red[1][lane] + red[2][lane] + red[3][lane];
    acc = red2[0][lane] + red2[1][lane] + red2[2][lane] + red2[3][lane];
    out[(size_t)g * NRS + f] = acc / (ss + 1e-16f);
  }
}

// ---- orchestration ----------------------------------------------------------

extern "C" void kernel_launch(void* const* d_in, const int* in_sizes, int n_in,
                              void* d_out, int out_size, void* d_ws, size_t ws_size,
                              hipStream_t stream){
  const float* x0   = (const float*)d_in[0];
  const int*   eidx = (const int*)d_in[1];
  const int*   etyp = (const int*)d_in[2];
  const int*   batch= (const int*)d_in[3];
  const float* Wf   = (const float*)d_in[4];
  const float* qf   = (const float*)d_in[5];
  const float* kf   = (const float*)d_in[6];
  const float* bf   = (const float*)d_in[7];
  const float* Ws   = (const float*)d_in[8];
  const float* qs   = (const float*)d_in[9];
  const float* ks   = (const float*)d_in[10];
  const float* bs   = (const float*)d_in[11];
  const float* tp   = (const float*)d_in[12];

  float* gout = (float*)d_out;                 // [256][832]
  float* nrep = gout + (size_t)NG * NRS;       // [50000][832]

  char* w = (char*)d_ws;
  float* XR   = (float*)w;  w += (size_t)NN * XRS * 4;        // 38.4 MB
  float* QK   = (float*)w;  w += (size_t)NN * 8 * 4;          // 1.6 MB
  int*   rowp = (int*)w;    w += (size_t)(NN + 2) * 4;
  int*   cnts = (int*)w;    w += (size_t)NN * 4;
  int*   gst  = (int*)w;    w += (size_t)(NG + 2) * 4;
  int*   bsum = (int*)w;    w += 64 * 4;
  int*   csr  = (int*)w;    w += (size_t)NE * 4;              // 6.4 MB

  const int* srcv = eidx;
  const int* dstv = eidx + NE;

  const int NB = (NN + 1023) / 1024;  // 49

  // CSR by dst + graph boundaries (once per call, reused by all 13 layers)
  hipMemsetAsync(cnts, 0, (size_t)NN * 4, stream);
  hist_kernel<<<(NE + 255) / 256, 256, 0, stream>>>(dstv, cnts);
  scan1_kernel<<<NB, 1024, 0, stream>>>(cnts, rowp, bsum);
  scan2_kernel<<<1, 64, 0, stream>>>(bsum, rowp, NB);
  scan3_kernel<<<NB, 1024, 0, stream>>>(rowp, bsum);
  hipMemsetAsync(cnts, 0, (size_t)NN * 4, stream);
  scatter_kernel<<<(NE + 255) / 256, 256, 0, stream>>>(srcv, dstv, etyp, rowp, cnts, csr);
  gstart_kernel<<<(NN + 256) / 256, 256, 0, stream>>>(batch, gst);

  for (int l = 0; l < 13; ++l){
    int K = (l == 0) ? IND : HID;
    const float* W  = (l == 0) ? Wf : (Ws + (size_t)(l - 1) * NREL * HID * HID);
    const float* q  = (l == 0) ? qf : (qs + (size_t)(l - 1) * HID);
    const float* kv = (l == 0) ? kf : (ks + (size_t)(l - 1) * HID);
    const float* b  = (l == 0) ? bf : (bs + (size_t)(l - 1) * HID);
    const float* x  = (l == 0) ? x0 : (nrep + (size_t)(l - 1) * HID);
    int ldx = (l == 0) ? IND : NRS;
    mm_kernel<<<(NN + 63) / 64, 256, 0, stream>>>(x, ldx, K, W, q, kv, XR, QK);
    edge_kernel<<<(NN + 3) / 4, 256, 0, stream>>>(XR, QK, csr, rowp, b, nrep + (size_t)l * HID);
  }
  dim3 ag(NG, 13);
  agg_kernel<<<ag, 256, 0, stream>>>(nrep, gst, tp, gout);
}